// Round 1
// baseline (150.710 us; speedup 1.0000x reference)
//
#include <hip/hip_runtime.h>

// MultiboxLoss anchor matching: B=64, T=100, A=8732, NUM_CLASSES=21
// out = [loc (B,A,4) f32][conf (B,A) written as f32 values]
#define BB 64
#define TT 100
#define AA 8732

// Bit-exact (vs numpy f32) IoU. _rn intrinsics block fp-contract fusion so
// mul/add rounding matches numpy's unfused op-by-op evaluation.
__device__ __forceinline__ float iou_f(float bx1, float by1, float bx2, float by2, float areab,
                                       float ax1, float ay1, float ax2, float ay2, float areaa) {
    float dx = fmaxf(__fsub_rn(fminf(bx2, ax2), fmaxf(bx1, ax1)), 0.0f);
    float dy = fmaxf(__fsub_rn(fminf(by2, ay2), fmaxf(by1, ay1)), 0.0f);
    float inter = __fmul_rn(dx, dy);
    float uni = __fsub_rn(__fadd_rn(areab, areaa), inter);
    return inter / uni;  // IEEE div (no fast-math), matches numpy
}

// Point-form anchor: must round-trip through cx +/- w/2 exactly like reference
__device__ __forceinline__ void anchor_pt(const float* __restrict__ an,
                                          float& ax1, float& ay1, float& ax2, float& ay2,
                                          float& areaa) {
    float acx = an[0], acy = an[1], aw = an[2], ah = an[3];
    float hx = __fmul_rn(aw, 0.5f), hy = __fmul_rn(ah, 0.5f);
    ax1 = __fsub_rn(acx, hx);
    ay1 = __fsub_rn(acy, hy);
    ax2 = __fadd_rn(acx, hx);
    ay2 = __fadd_rn(acy, hy);
    areaa = __fmul_rn(__fsub_rn(ax2, ax1), __fsub_rn(ay2, ay1));
}

// K1: one block per (b,t); argmax_a iou[t][a], first-occurrence on ties.
// Packed key: larger value wins; on equal value, smaller anchor index wins.
__global__ __launch_bounds__(256) void k_anchor_argmax(const float* __restrict__ targets,
                                                       const float* __restrict__ anchors,
                                                       int* __restrict__ anchor_index) {
    const int bt = blockIdx.x;  // b*TT + t
    const float* tg = targets + (size_t)bt * 5;
    const float bx1 = tg[0], by1 = tg[1], bx2 = tg[2], by2 = tg[3];
    const float areab = __fmul_rn(__fsub_rn(bx2, bx1), __fsub_rn(by2, by1));

    unsigned long long best = 0ULL;  // value=0.0 @ anchor 0xFFFFFFFF: any real (a,v) beats it
    for (int a = threadIdx.x; a < AA; a += 256) {
        float ax1, ay1, ax2, ay2, areaa;
        anchor_pt(anchors + (size_t)a * 4, ax1, ay1, ax2, ay2, areaa);
        float v = iou_f(bx1, by1, bx2, by2, areab, ax1, ay1, ax2, ay2, areaa);
        unsigned long long key =
            ((unsigned long long)__float_as_uint(v) << 32) | (unsigned long long)(0xFFFFFFFFu - (unsigned)a);
        if (key > best) best = key;
    }
    // wave (64-lane) reduction
    #pragma unroll
    for (int off = 32; off > 0; off >>= 1) {
        unsigned long long o = __shfl_down(best, off, 64);
        if (o > best) best = o;
    }
    __shared__ unsigned long long sh[4];
    const int lane = threadIdx.x & 63, wv = threadIdx.x >> 6;
    if (lane == 0) sh[wv] = best;
    __syncthreads();
    if (threadIdx.x == 0) {
        best = sh[0];
        #pragma unroll
        for (int i = 1; i < 4; ++i)
            if (sh[i] > best) best = sh[i];
        anchor_index[bt] = (int)(0xFFFFFFFFu - (unsigned)(best & 0xFFFFFFFFu));
    }
}

// K2: one thread per (b,a). Per-anchor max/argmax over the 100 targets
// (recomputed from staged shared targets), last-wins override from the
// anchor_index list, then the loc/conf encode.
__global__ __launch_bounds__(256) void k_output(const float* __restrict__ targets,
                                                const float* __restrict__ anchors,
                                                const int* __restrict__ anchor_index,
                                                float* __restrict__ out) {
    const int b = blockIdx.y;
    const int a = blockIdx.x * 256 + threadIdx.x;

    __shared__ float sh_t[TT][6];  // x1,y1,x2,y2,label,area_b
    __shared__ int sh_ai[TT];
    for (int t = threadIdx.x; t < TT; t += 256) {
        const float* tg = targets + ((size_t)b * TT + t) * 5;
        float x1 = tg[0], y1 = tg[1], x2 = tg[2], y2 = tg[3];
        sh_t[t][0] = x1; sh_t[t][1] = y1; sh_t[t][2] = x2; sh_t[t][3] = y2;
        sh_t[t][4] = tg[4];
        sh_t[t][5] = __fmul_rn(__fsub_rn(x2, x1), __fsub_rn(y2, y1));  // stored: no contraction
        sh_ai[t] = anchor_index[b * TT + t];
    }
    __syncthreads();
    if (a >= AA) return;

    const float* an = anchors + (size_t)a * 4;
    const float acx = an[0], acy = an[1], aw = an[2], ah = an[3];
    float ax1, ay1, ax2, ay2, areaa;
    anchor_pt(an, ax1, ay1, ax2, ay2, areaa);

    float best = -1.0f;  // all iou >= 0, so t=0 always taken first
    int gi = 0;
    for (int t = 0; t < TT; ++t) {
        float v = iou_f(sh_t[t][0], sh_t[t][1], sh_t[t][2], sh_t[t][3], sh_t[t][5],
                        ax1, ay1, ax2, ay2, areaa);
        if (v > best) { best = v; gi = t; }  // strict >: first occurrence
    }
    float ov = best;
    for (int t = 0; t < TT; ++t) {
        if (sh_ai[t] == a) { ov = 1.0f; gi = t; }  // ascending t: last-wins scatter
    }

    const float mx1 = sh_t[gi][0], my1 = sh_t[gi][1], mx2 = sh_t[gi][2], my2 = sh_t[gi][3];
    const float cx = (mx1 + mx2) * 0.5f, cy = (my1 + my2) * 0.5f;
    const float w = mx2 - mx1, h = my2 - my1;
    const float l0 = (cx - acx) / (0.1f * aw);
    const float l1 = (cy - acy) / (0.1f * ah);
    const float l2 = logf(w / aw) / 0.2f;
    const float l3 = logf(h / ah) / 0.2f;

    const size_t base = ((size_t)b * AA + a) * 4;
    out[base + 0] = l0;
    out[base + 1] = l1;
    out[base + 2] = l2;
    out[base + 3] = l3;

    float conf = (ov < 0.5f) ? 0.0f : (float)(int)(sh_t[gi][4] + 1.0f);
    out[(size_t)BB * AA * 4 + (size_t)b * AA + a] = conf;
}

extern "C" void kernel_launch(void* const* d_in, const int* in_sizes, int n_in,
                              void* d_out, int out_size, void* d_ws, size_t ws_size,
                              hipStream_t stream) {
    const float* targets = (const float*)d_in[0];  // (B,T,5)
    const float* anchors = (const float*)d_in[1];  // (A,4)
    float* out = (float*)d_out;
    int* anchor_index = (int*)d_ws;  // B*T ints = 25.6 KB

    k_anchor_argmax<<<BB * TT, 256, 0, stream>>>(targets, anchors, anchor_index);
    dim3 grid((AA + 255) / 256, BB);
    k_output<<<grid, 256, 0, stream>>>(targets, anchors, anchor_index, out);
}

// Round 2
// 139.974 us; speedup vs baseline: 1.0767x; 1.0767x over previous
//
#include <hip/hip_runtime.h>

// MultiboxLoss anchor matching: B=64, T=100, A=8732, NUM_CLASSES=21
// out = [loc (B,A,4) f32][conf (B,A) as f32]
// Round 2: single-pass fused IoU (each of the 55.9M IoUs computed once).
//   ws layout: [0, 51200): u64 keys[B*T]   — packed (iou_bits<<32)|(~anchor), atomicMax-combined
//              [51200, +B*A*2): u16 pa[B*A] — per-anchor (gi | pos<<7)
#define BB 64
#define TT 100
#define AA 8732
#define CHUNK 512                         // anchors per phase-A block (256 thr x 2)
#define NCHUNK ((AA + CHUNK - 1) / CHUNK) // 18

typedef unsigned long long u64;
typedef unsigned int u32;
typedef unsigned short u16;

// Bit-exact (vs numpy f32) IoU: _rn intrinsics block fp-contract fusion.
__device__ __forceinline__ float iou_f(float bx1, float by1, float bx2, float by2, float areab,
                                       float ax1, float ay1, float ax2, float ay2, float areaa) {
    float dx = fmaxf(__fsub_rn(fminf(bx2, ax2), fmaxf(bx1, ax1)), 0.0f);
    float dy = fmaxf(__fsub_rn(fminf(by2, ay2), fmaxf(by1, ay1)), 0.0f);
    float inter = __fmul_rn(dx, dy);
    float uni = __fsub_rn(__fadd_rn(areab, areaa), inter);
    return inter / uni;  // IEEE div, matches numpy
}

__global__ __launch_bounds__(256) void k_init(u64* __restrict__ keys) {
    int i = blockIdx.x * 256 + threadIdx.x;
    if (i < BB * TT) keys[i] = 0ULL;
}

// Fused pass: block = (b, 512-anchor chunk), 2 anchors per thread.
// Produces: pa[b*A+a] = gi(7b) | pos(bit7);  keys[b*T+t] = packed per-target argmax.
__global__ __launch_bounds__(256) void k_phaseA(const float* __restrict__ targets,
                                                const float* __restrict__ anchors,
                                                u64* __restrict__ keys,
                                                u16* __restrict__ pa) {
    const int b = blockIdx.y;
    const int a0 = blockIdx.x * CHUNK + threadIdx.x * 2;  // anchors a0, a0+1 (AA even => pair valid together)
    const bool valid = a0 < AA;

    __shared__ float sh_t[TT][8];   // x1,y1,x2,y2,area_b (stride 8 for b128 alignment)
    __shared__ u64 sh_red[TT][4];   // per-wave per-target winners

    for (int t = threadIdx.x; t < TT; t += 256) {
        const float* tg = targets + ((size_t)b * TT + t) * 5;
        float x1 = tg[0], y1 = tg[1], x2 = tg[2], y2 = tg[3];
        sh_t[t][0] = x1; sh_t[t][1] = y1; sh_t[t][2] = x2; sh_t[t][3] = y2;
        sh_t[t][4] = __fmul_rn(__fsub_rn(x2, x1), __fsub_rn(y2, y1));
    }
    __syncthreads();

    // Anchor point-form, computed once per thread (dummies for OOB lanes keep uni>0).
    float ax10 = 0.f, ay10 = 0.f, ax20 = 0.f, ay20 = 0.f, aa0 = 1.f;
    float ax11 = 0.f, ay11 = 0.f, ax21 = 0.f, ay21 = 0.f, aa1 = 1.f;
    if (valid) {
        const float4* anc = (const float4*)(anchors + (size_t)a0 * 4);
        float4 c0 = anc[0], c1 = anc[1];
        float hx0 = __fmul_rn(c0.z, 0.5f), hy0 = __fmul_rn(c0.w, 0.5f);
        ax10 = __fsub_rn(c0.x, hx0); ay10 = __fsub_rn(c0.y, hy0);
        ax20 = __fadd_rn(c0.x, hx0); ay20 = __fadd_rn(c0.y, hy0);
        aa0 = __fmul_rn(__fsub_rn(ax20, ax10), __fsub_rn(ay20, ay10));
        float hx1 = __fmul_rn(c1.z, 0.5f), hy1 = __fmul_rn(c1.w, 0.5f);
        ax11 = __fsub_rn(c1.x, hx1); ay11 = __fsub_rn(c1.y, hy1);
        ax21 = __fadd_rn(c1.x, hx1); ay21 = __fadd_rn(c1.y, hy1);
        aa1 = __fmul_rn(__fsub_rn(ax21, ax11), __fsub_rn(ay21, ay11));
    }

    const int lane = threadIdx.x & 63, wv = threadIdx.x >> 6;
    float best0 = -1.f, best1 = -1.f;
    int gi0 = 0, gi1 = 0;

    for (int t = 0; t < TT; ++t) {
        float4 box = *(const float4*)&sh_t[t][0];   // broadcast, conflict-free
        float areab = sh_t[t][4];
        float v0 = iou_f(box.x, box.y, box.z, box.w, areab, ax10, ay10, ax20, ay20, aa0);
        float v1 = iou_f(box.x, box.y, box.z, box.w, areab, ax11, ay11, ax21, ay21, aa1);
        v0 = valid ? v0 : -1.f;
        v1 = valid ? v1 : -1.f;
        // per-anchor argmax over t: strict >, first-t-wins
        if (v0 > best0) { best0 = v0; gi0 = t; }
        if (v1 > best1) { best1 = v1; gi1 = t; }
        // per-target argmax over anchors: local pair (first-index-wins on tie)
        float vm = v0; int ga = a0;
        if (v1 > vm) { vm = v1; ga = a0 + 1; }
        // wave max (value only), then smallest matching lane = smallest anchor
        float wm = vm;
        #pragma unroll
        for (int off = 1; off < 64; off <<= 1)
            wm = fmaxf(wm, __shfl_xor(wm, off, 64));
        u64 mask = __ballot(vm == wm);
        int wl = (int)__ffsll((long long)mask) - 1;
        int wga = __shfl(ga, wl, 64);
        if (lane == 0) {
            u64 key = (wm < 0.f) ? 0ULL
                    : (((u64)__float_as_uint(wm) << 32) | (u64)(0xFFFFFFFFu - (u32)wga));
            sh_red[t][wv] = key;
        }
    }
    __syncthreads();

    if (threadIdx.x < TT) {
        u64 m0 = sh_red[threadIdx.x][0], m1 = sh_red[threadIdx.x][1];
        u64 m2 = sh_red[threadIdx.x][2], m3 = sh_red[threadIdx.x][3];
        u64 m = m0 > m1 ? m0 : m1;
        if (m2 > m) m = m2;
        if (m3 > m) m = m3;
        if (m) atomicMax(&keys[b * TT + threadIdx.x], m);
    }

    if (valid) {
        u32 f0 = (u32)gi0 | (best0 >= 0.5f ? 0x80u : 0u);
        u32 f1 = (u32)gi1 | (best1 >= 0.5f ? 0x80u : 0u);
        *(u32*)(pa + (size_t)b * AA + a0) = f0 | (f1 << 16);  // 4B-aligned: AA,a0 even
    }
}

// Encode: thread per (b,a). Override applied via LDS atomicMax scatter
// (value 0x100|t is monotone in t => last-wins, matching .at[].set semantics).
__global__ __launch_bounds__(256) void k_encode(const float* __restrict__ targets,
                                                const float* __restrict__ anchors,
                                                const u64* __restrict__ keys,
                                                const u16* __restrict__ pa,
                                                float* __restrict__ out) {
    const int b = blockIdx.y;
    const int a = blockIdx.x * 256 + threadIdx.x;

    __shared__ float sh_t[TT][6];   // x1,y1,x2,y2,label
    __shared__ u32 sh_ov[256];

    sh_ov[threadIdx.x] = 0;
    __syncthreads();
    for (int t = threadIdx.x; t < TT; t += 256) {
        const float* tg = targets + ((size_t)b * TT + t) * 5;
        sh_t[t][0] = tg[0]; sh_t[t][1] = tg[1];
        sh_t[t][2] = tg[2]; sh_t[t][3] = tg[3];
        sh_t[t][4] = tg[4];
        u32 at = 0xFFFFFFFFu - (u32)(keys[b * TT + t] & 0xFFFFFFFFu);
        if ((at >> 8) == (u32)blockIdx.x)
            atomicMax(&sh_ov[at & 255], 0x100u | (u32)t);
    }
    __syncthreads();
    if (a >= AA) return;

    u32 ov = sh_ov[threadIdx.x];
    u32 v = pa[(size_t)b * AA + a];
    int gi; bool pos;
    if (ov) { gi = (int)(ov & 0x7F); pos = true; }
    else     { gi = (int)(v & 0x7F); pos = (v & 0x80) != 0; }

    const float4 anc = *(const float4*)(anchors + (size_t)a * 4);
    const float mx1 = sh_t[gi][0], my1 = sh_t[gi][1], mx2 = sh_t[gi][2], my2 = sh_t[gi][3];
    const float cx = (mx1 + mx2) * 0.5f, cy = (my1 + my2) * 0.5f;
    const float w = mx2 - mx1, h = my2 - my1;
    const float l0 = (cx - anc.x) / (0.1f * anc.z);
    const float l1 = (cy - anc.y) / (0.1f * anc.w);
    const float l2 = logf(w / anc.z) / 0.2f;
    const float l3 = logf(h / anc.w) / 0.2f;

    const size_t base = ((size_t)b * AA + a) * 4;
    *(float4*)(out + base) = make_float4(l0, l1, l2, l3);
    float conf = pos ? (float)(int)(sh_t[gi][4] + 1.0f) : 0.0f;
    out[(size_t)BB * AA * 4 + (size_t)b * AA + a] = conf;
}

extern "C" void kernel_launch(void* const* d_in, const int* in_sizes, int n_in,
                              void* d_out, int out_size, void* d_ws, size_t ws_size,
                              hipStream_t stream) {
    const float* targets = (const float*)d_in[0];  // (B,T,5)
    const float* anchors = (const float*)d_in[1];  // (A,4)
    float* out = (float*)d_out;
    u64* keys = (u64*)d_ws;                         // 51.2 KB
    u16* pa = (u16*)((char*)d_ws + (size_t)BB * TT * 8);  // 1.09 MB

    k_init<<<(BB * TT + 255) / 256, 256, 0, stream>>>(keys);
    dim3 gA(NCHUNK, BB);
    k_phaseA<<<gA, 256, 0, stream>>>(targets, anchors, keys, pa);
    dim3 gE((AA + 255) / 256, BB);
    k_encode<<<gE, 256, 0, stream>>>(targets, anchors, keys, pa, out);
}